// Round 4
// baseline (26082.047 us; speedup 1.0000x reference)
//
#include <hip/hip_runtime.h>

// ---------------------------------------------------------------------------
// MultilayerGRU  B=64 S=1024 I=128 H=512 L=3 O=128
// Round 4: single fused persistent kernel, all 3 layers pipelined.
//   - 96 WGs = 3 layers x 32 col-slices; 768 thr = 12 waves = 3 roles(r,z,g)
//     x 4 M-tiles (64 batch rows). 1 WG/CU (LDS ~106 KB) -> co-residency.
//   - input projection folded into MFMA K-extension ([h_l(t-1); x_t]);
//     layer0 x from static Xt; layers 1,2 x = upstream h via 256-deep ring.
//   - write-through relaxed atomics + vmcnt(0)-ordered flags (round-3 proto).
//   - critical path ~1026 steps instead of 3072.
// ---------------------------------------------------------------------------

typedef float f32x4 __attribute__((ext_vector_type(4)));
typedef __bf16 bf16x8 __attribute__((ext_vector_type(8)));

__device__ __forceinline__ unsigned short f2bf(float x) {
  unsigned int u = __builtin_bit_cast(unsigned int, x);
  u += 0x7fffu + ((u >> 16) & 1u);   // round-to-nearest-even
  return (unsigned short)(u >> 16);
}
__device__ __forceinline__ f32x4 mfma16(int4 a, int4 b, f32x4 c) {
  return __builtin_amdgcn_mfma_f32_16x16x32_bf16(
      __builtin_bit_cast(bf16x8, a), __builtin_bit_cast(bf16x8, b), c, 0, 0, 0);
}
__device__ __forceinline__ float sig_(float x) { return 1.0f / (1.0f + __expf(-x)); }
__device__ __forceinline__ float tanh_(float x) {
  float ax = fabsf(x);
  float e  = __expf(2.0f * ax);
  float t  = 1.0f - 2.0f / (e + 1.0f);
  return x < 0.0f ? -t : t;
}

// ---- write-through (coherence-point) relaxed atomics: no cache maintenance ----
__device__ __forceinline__ unsigned long long ld_wt64(const unsigned long long* p) {
  return __hip_atomic_load(p, __ATOMIC_RELAXED, __HIP_MEMORY_SCOPE_AGENT);
}
__device__ __forceinline__ void st_wt16(unsigned short* p, unsigned short v) {
  __hip_atomic_store(p, v, __ATOMIC_RELAXED, __HIP_MEMORY_SCOPE_AGENT);
}
__device__ __forceinline__ void st_flag(int* p, int v) {
  __hip_atomic_store(p, v, __ATOMIC_RELAXED, __HIP_MEMORY_SCOPE_AGENT);
}
__device__ __forceinline__ void poll_ge(const int* f, int need) {
  int lane = threadIdx.x & 63;
  int v = need;
  if (lane < 32) v = __hip_atomic_load((int*)(f + lane), __ATOMIC_RELAXED, __HIP_MEMORY_SCOPE_AGENT);
  while (__any(v < need)) {
    __builtin_amdgcn_s_sleep(1);
    if (lane < 32) v = __hip_atomic_load((int*)(f + lane), __ATOMIC_RELAXED, __HIP_MEMORY_SCOPE_AGENT);
  }
}
__device__ __forceinline__ void load_frags16(const unsigned short* base, int4* af) {
  const unsigned long long* p = (const unsigned long long*)base;
#pragma unroll
  for (int kc = 0; kc < 16; kc++) {
    unsigned long long lo = ld_wt64(p + kc * 8);
    unsigned long long hi = ld_wt64(p + kc * 8 + 1);
    af[kc] = make_int4((int)(unsigned int)lo, (int)(unsigned int)(lo >> 32),
                       (int)(unsigned int)hi, (int)(unsigned int)(hi >> 32));
  }
}

// ---------------------------------------------------------------------------
__global__ void cvt_bf16(const float* __restrict__ src, unsigned short* __restrict__ dst, int n4) {
  int i = blockIdx.x * blockDim.x + threadIdx.x;
  if (i < n4) {
    float4 v = *(const float4*)(src + (size_t)i * 4);
    ushort4 o;
    o.x = f2bf(v.x); o.y = f2bf(v.y); o.z = f2bf(v.z); o.w = f2bf(v.w);
    *(ushort4*)(dst + (size_t)i * 4) = o;
  }
}

// X (64,1024,128) f32 -> Xt row (t*64+b), 128 bf16
__global__ void xt_k(const float* __restrict__ X, unsigned short* __restrict__ Xt) {
  int idx = blockIdx.x * 256 + threadIdx.x;
  int i4 = idx & 31, rest = idx >> 5;
  int t = rest & 1023, b = rest >> 10;
  float4 v = *(const float4*)(X + (size_t)(b * 1024 + t) * 128 + i4 * 4);
  ushort4 o;
  o.x = f2bf(v.x); o.y = f2bf(v.y); o.z = f2bf(v.z); o.w = f2bf(v.w);
  *(ushort4*)(Xt + (size_t)(t * 64 + b) * 128 + i4 * 4) = o;
}

// ---------------------------------------------------------------------------
// C[M,N] = A[M,K] @ W[N,K]^T  (bf16). mode 0: bf16 out; mode 2: fp32+bias,
// row remap m=(t*64+b) -> out row b*1024+t (final Y).
// ---------------------------------------------------------------------------
__global__ __launch_bounds__(256)
void gemm_bt(const unsigned short* __restrict__ A, const unsigned short* __restrict__ W,
             void* __restrict__ Cout, const float* __restrict__ bias,
             int M, int N, int K, int mode) {
  __shared__ unsigned short As[128][72];
  __shared__ unsigned short Bs[128][72];
  const int tid  = threadIdx.x;
  const int lane = tid & 63;
  const int wave = tid >> 6;
  const int wr = wave >> 1, wc = wave & 1;
  const int m0 = blockIdx.x * 128, n0 = blockIdx.y * 128;

  f32x4 acc[4][4];
  for (int i = 0; i < 4; i++)
    for (int j = 0; j < 4; j++) acc[i][j] = f32x4{0.f, 0.f, 0.f, 0.f};

  for (int k0 = 0; k0 < K; k0 += 64) {
    int4 va[4], vb[4];
#pragma unroll
    for (int it = 0; it < 4; it++) {
      int q = tid + it * 256;
      int r = q >> 3, kc = q & 7;
      va[it] = *(const int4*)(A + (size_t)(m0 + r) * K + k0 + kc * 8);
      vb[it] = *(const int4*)(W + (size_t)(n0 + r) * K + k0 + kc * 8);
    }
    __syncthreads();
#pragma unroll
    for (int it = 0; it < 4; it++) {
      int q = tid + it * 256;
      int r = q >> 3, kc = q & 7;
      *(int4*)&As[r][kc * 8] = va[it];
      *(int4*)&Bs[r][kc * 8] = vb[it];
    }
    __syncthreads();
#pragma unroll
    for (int kc = 0; kc < 2; kc++) {
      int koff = kc * 32 + (lane >> 4) * 8;
      int4 af[4], bfr[4];
#pragma unroll
      for (int mt = 0; mt < 4; mt++) af[mt]  = *(const int4*)&As[wr * 64 + mt * 16 + (lane & 15)][koff];
#pragma unroll
      for (int nt = 0; nt < 4; nt++) bfr[nt] = *(const int4*)&Bs[wc * 64 + nt * 16 + (lane & 15)][koff];
#pragma unroll
      for (int mt = 0; mt < 4; mt++)
#pragma unroll
        for (int nt = 0; nt < 4; nt++)
          acc[mt][nt] = mfma16(af[mt], bfr[nt], acc[mt][nt]);
    }
  }

#pragma unroll
  for (int mt = 0; mt < 4; mt++)
#pragma unroll
    for (int nt = 0; nt < 4; nt++)
#pragma unroll
      for (int rg = 0; rg < 4; rg++) {
        int m = m0 + wr * 64 + mt * 16 + (lane >> 4) * 4 + rg;
        int n = n0 + wc * 64 + nt * 16 + (lane & 15);
        float v = acc[mt][nt][rg];
        if (mode == 0) {
          ((unsigned short*)Cout)[(size_t)m * N + n] = f2bf(v);
        } else {
          ((float*)Cout)[(size_t)((m & 63) * 1024 + (m >> 6)) * N + n] = v + bias[n];
        }
      }
}

// ---------------------------------------------------------------------------
// Fused 3-layer pipelined recurrence.
// Flags (ints): hfl[3][32] (hfl = last_published_t + 2; h(-1) -> 1),
//               ufl[3][32] (u(t) -> t+1),
//               cpr[3][32] (consumer progress, layers 1,2; value = t).
// ---------------------------------------------------------------------------
__global__ __launch_bounds__(768)
void gru_fused(const float* __restrict__ Whz, const float* __restrict__ Whr,
               const float* __restrict__ Whg,
               const float* __restrict__ bz, const float* __restrict__ br,
               const float* __restrict__ bg,
               const float* __restrict__ Wx0z, const float* __restrict__ Wx0r,
               const float* __restrict__ Wx0g,
               const float* __restrict__ Wxz, const float* __restrict__ Wxr,
               const float* __restrict__ Wxg,
               const unsigned short* __restrict__ Xt,   // (S*B,128) bf16
               const float* __restrict__ h0,            // (B,L,H) fp32
               unsigned short* __restrict__ ring,       // 3 x 256 x (64*512) bf16
               unsigned short* __restrict__ ubc,        // 3 x (64*512) bf16
               int* __restrict__ flags,
               unsigned short* __restrict__ Hbuf,       // (S*B,512) bf16 (layer2)
               float* __restrict__ hidout) {            // (B,L,H) fp32
  const int bid  = blockIdx.x;
  const int L    = bid >> 5;         // layer 0..2
  const int mem  = bid & 31;         // col slice
  const int cbase = mem * 16;
  const int tid  = threadIdx.x;
  const int lane = tid & 63;
  const int wave = tid >> 6;         // 0..11
  const int mtile = wave & 3;        // M-tile (16 batch rows)
  const int role  = wave >> 2;       // 0=r, 1=z, 2=g

  __shared__ unsigned short Whs[3][16][520];   // 0=z,1=r,2=g
  __shared__ unsigned short Wxs[3][16][520];
  __shared__ float hloc[64][17];
  __shared__ float zbuf[64][17];
  __shared__ float bsh[3][16];

  // ---- stage hidden weights fp32 -> bf16 LDS ----
  const float* whsrc[3] = { Whz, Whr, Whg };
  for (int m = 0; m < 3; m++) {
    const float* src = whsrc[m] + (size_t)L * 262144 + (size_t)cbase * 512;
    for (int q = tid; q < 2048; q += 768) {
      int c = q >> 7, k4 = (q & 127) * 4;
      float4 v = *(const float4*)(src + c * 512 + k4);
      Whs[m][c][k4 + 0] = f2bf(v.x); Whs[m][c][k4 + 1] = f2bf(v.y);
      Whs[m][c][k4 + 2] = f2bf(v.z); Whs[m][c][k4 + 3] = f2bf(v.w);
    }
  }
  // ---- stage input weights ----
  if (L == 0) {
    const float* wxsrc[3] = { Wx0z, Wx0r, Wx0g };
    for (int m = 0; m < 3; m++) {
      const float* src = wxsrc[m] + (size_t)cbase * 128;
      for (int q = tid; q < 512; q += 768) {
        int c = q >> 5, k4 = (q & 31) * 4;
        float4 v = *(const float4*)(src + c * 128 + k4);
        Wxs[m][c][k4 + 0] = f2bf(v.x); Wxs[m][c][k4 + 1] = f2bf(v.y);
        Wxs[m][c][k4 + 2] = f2bf(v.z); Wxs[m][c][k4 + 3] = f2bf(v.w);
      }
    }
  } else {
    const float* wxsrc[3] = { Wxz, Wxr, Wxg };
    for (int m = 0; m < 3; m++) {
      const float* src = wxsrc[m] + (size_t)(L - 1) * 262144 + (size_t)cbase * 512;
      for (int q = tid; q < 2048; q += 768) {
        int c = q >> 7, k4 = (q & 127) * 4;
        float4 v = *(const float4*)(src + c * 512 + k4);
        Wxs[m][c][k4 + 0] = f2bf(v.x); Wxs[m][c][k4 + 1] = f2bf(v.y);
        Wxs[m][c][k4 + 2] = f2bf(v.z); Wxs[m][c][k4 + 3] = f2bf(v.w);
      }
    }
  }
  if (tid < 16) {
    bsh[0][tid] = bz[(size_t)L * 512 + cbase + tid];
    bsh[1][tid] = br[(size_t)L * 512 + cbase + tid];
    bsh[2][tid] = bg[(size_t)L * 512 + cbase + tid];
  }

  unsigned short* myring = ring + (size_t)L * 8388608;
  const unsigned short* upring = ring + (size_t)(L > 0 ? L - 1 : 0) * 8388608;
  unsigned short* myubc = ubc + (size_t)L * 32768;

  // ---- init h(-1): hloc + ring slot 0 ----
  for (int q = tid; q < 1024; q += 768) {
    int row = q >> 4, c = q & 15;
    float v = h0[(size_t)row * 1536 + L * 512 + cbase + c];
    hloc[row][c] = v;
    st_wt16(&myring[row * 512 + cbase + c], f2bf(v));
  }
  asm volatile("s_waitcnt vmcnt(0)" ::: "memory");
  __syncthreads();

  int* hfl = flags;
  int* ufl = flags + 96;
  int* cpr = flags + 192;
  if (tid == 0) st_flag(&hfl[L * 32 + mem], 1);

  const int m16  = mtile * 16;
  const int arow = m16 + (lane & 15);   // batch row for A-fragments
  const int kq   = lane >> 4;           // K-octet selector
  const int wsel = (role == 0) ? 1 : ((role == 1) ? 0 : 2);
  const unsigned short* whrow = &Whs[wsel][lane & 15][kq * 8];
  const unsigned short* wxrow = &Wxs[wsel][lane & 15][kq * 8];

  f32x4 gx = f32x4{0.f, 0.f, 0.f, 0.f};

  for (int t = 0; t < 1024; t++) {
    if (role < 2) {
      // ---------------- phase 1: r (role0) / z (role1) ----------------
      int4 xf[16];
      if (L > 0) {
        poll_ge(hfl + (L - 1) * 32, t + 2);       // x = h_{L-1}(t)
        const unsigned short* xr = upring + (size_t)((t + 1) & 255) * 32768 + arow * 512 + kq * 8;
        load_frags16(xr, xf);
      } else {
#pragma unroll
        for (int kc = 0; kc < 4; kc++)
          xf[kc] = *(const int4*)(Xt + (size_t)(t * 64 + arow) * 128 + kq * 8 + kc * 32);
      }
      poll_ge(hfl + L * 32, t + 1);               // own h(t-1)
      int4 hf[16];
      const unsigned short* hr = myring + (size_t)(t & 255) * 32768 + arow * 512 + kq * 8;
      load_frags16(hr, hf);

      f32x4 a0 = f32x4{0.f, 0.f, 0.f, 0.f}, a1 = f32x4{0.f, 0.f, 0.f, 0.f};
      if (L > 0) {
#pragma unroll
        for (int kc = 0; kc < 16; kc += 2) {
          a0 = mfma16(xf[kc],     *(const int4*)(wxrow + kc * 32),       a0);
          a1 = mfma16(xf[kc + 1], *(const int4*)(wxrow + (kc + 1) * 32), a1);
        }
      } else {
#pragma unroll
        for (int kc = 0; kc < 4; kc++)
          a0 = mfma16(xf[kc], *(const int4*)(wxrow + kc * 32), a0);
      }
#pragma unroll
      for (int kc = 0; kc < 16; kc += 2) {
        a0 = mfma16(hf[kc],     *(const int4*)(whrow + kc * 32),       a0);
        a1 = mfma16(hf[kc + 1], *(const int4*)(whrow + (kc + 1) * 32), a1);
      }
      f32x4 acc = a0 + a1;
      if (role == 0) {
#pragma unroll
        for (int rg = 0; rg < 4; rg++) {
          int row = m16 + kq * 4 + rg;
          float rv = sig_(acc[rg] + bsh[1][lane & 15]);
          float uv = rv * hloc[row][lane & 15];
          st_wt16(&myubc[row * 512 + cbase + (lane & 15)], f2bf(uv));
        }
        asm volatile("s_waitcnt vmcnt(0)" ::: "memory");
      } else {
#pragma unroll
        for (int rg = 0; rg < 4; rg++)
          zbuf[m16 + kq * 4 + rg][lane & 15] = sig_(acc[rg] + bsh[0][lane & 15]);
      }
    } else {
      // ---------------- phase 1 (g): gx = Wxg . x ----------------
      gx = f32x4{0.f, 0.f, 0.f, 0.f};
      int4 xf[16];
      if (L > 0) {
        poll_ge(hfl + (L - 1) * 32, t + 2);
        const unsigned short* xr = upring + (size_t)((t + 1) & 255) * 32768 + arow * 512 + kq * 8;
        load_frags16(xr, xf);
        f32x4 c0 = f32x4{0.f, 0.f, 0.f, 0.f}, c1 = f32x4{0.f, 0.f, 0.f, 0.f};
#pragma unroll
        for (int kc = 0; kc < 16; kc += 2) {
          c0 = mfma16(xf[kc],     *(const int4*)(wxrow + kc * 32),       c0);
          c1 = mfma16(xf[kc + 1], *(const int4*)(wxrow + (kc + 1) * 32), c1);
        }
        gx = c0 + c1;
      } else {
#pragma unroll
        for (int kc = 0; kc < 4; kc++) {
          int4 x1 = *(const int4*)(Xt + (size_t)(t * 64 + arow) * 128 + kq * 8 + kc * 32);
          gx = mfma16(x1, *(const int4*)(wxrow + kc * 32), gx);
        }
      }
    }
    __syncthreads();                               // barrier A (u stores acked)
    if (tid == 0) st_flag(&ufl[L * 32 + mem], t + 1);

    if (role == 2) {
      // ---------------- phase 2 (g): h update ----------------
      poll_ge(ufl + L * 32, t + 1);
      int4 uf[16];
      const unsigned short* ur = myubc + arow * 512 + kq * 8;
      load_frags16(ur, uf);
      f32x4 b0 = f32x4{0.f, 0.f, 0.f, 0.f}, b1 = f32x4{0.f, 0.f, 0.f, 0.f};
#pragma unroll
      for (int kc = 0; kc < 16; kc += 2) {
        b0 = mfma16(uf[kc],     *(const int4*)(whrow + kc * 32),       b0);
        b1 = mfma16(uf[kc + 1], *(const int4*)(whrow + (kc + 1) * 32), b1);
      }
      f32x4 acc = gx + b0 + b1;
      // back-pressure: don't overwrite ring slots downstream hasn't consumed
      if (L < 2 && t >= 224 && (t & 31) == 0)
        poll_ge(cpr + (L + 1) * 32, t - 160);
      unsigned short* hw = myring + (size_t)((t + 1) & 255) * 32768;
#pragma unroll
      for (int rg = 0; rg < 4; rg++) {
        int row = m16 + kq * 4 + rg;
        float gv = tanh_(acc[rg] + bsh[2][lane & 15]);
        float z  = zbuf[row][lane & 15];
        float h  = hloc[row][lane & 15];
        float hn = z * h + (1.0f - z) * gv;
        hloc[row][lane & 15] = hn;
        unsigned short hb = f2bf(hn);
        st_wt16(&hw[row * 512 + cbase + (lane & 15)], hb);
        if (L == 2)
          Hbuf[(size_t)t * 32768 + row * 512 + cbase + (lane & 15)] = hb;
        if (t == 1023)
          hidout[(size_t)row * 1536 + L * 512 + cbase + (lane & 15)] = hn;
      }
      asm volatile("s_waitcnt vmcnt(0)" ::: "memory");
    }
    __syncthreads();                               // barrier B (h stores acked)
    if (tid == 0) {
      st_flag(&hfl[L * 32 + mem], t + 2);
      if (L > 0 && (t & 31) == 31) st_flag(&cpr[L * 32 + mem], t);
    }
  }
}

// ---------------------------------------------------------------------------
// launcher
// ---------------------------------------------------------------------------
extern "C" void kernel_launch(void* const* d_in, const int* in_sizes, int n_in,
                              void* d_out, int out_size, void* d_ws, size_t ws_size,
                              hipStream_t stream) {
  const float* X    = (const float*)d_in[0];
  const float* H0   = (const float*)d_in[1];
  const float* Wx0z = (const float*)d_in[2];
  const float* Wx0r = (const float*)d_in[3];
  const float* Wx0g = (const float*)d_in[4];
  const float* Wxz  = (const float*)d_in[5];
  const float* Wxr  = (const float*)d_in[6];
  const float* Wxg  = (const float*)d_in[7];
  const float* Whz  = (const float*)d_in[8];
  const float* Whr  = (const float*)d_in[9];
  const float* Whg  = (const float*)d_in[10];
  const float* bz   = (const float*)d_in[11];
  const float* br   = (const float*)d_in[12];
  const float* bg   = (const float*)d_in[13];
  const float* Wy   = (const float*)d_in[14];
  const float* by   = (const float*)d_in[15];

  char* w = (char*)d_ws;
  unsigned short* Xt   = (unsigned short*)(w + 0);            // 16,777,216
  unsigned short* Wyb  = (unsigned short*)(w + 16777216);     // 131,072
  unsigned short* ring = (unsigned short*)(w + 16908288);     // 50,331,648 (3 rings)
  unsigned short* ubc  = (unsigned short*)(w + 67239936);     // 196,608
  unsigned short* Hb   = (unsigned short*)(w + 67436544);     // 67,108,864
  int* flags           = (int*)(w + 134545408);               // 2048
  // total ~134.5 MB (fits: 138 MB layout was OK in rounds 2-3)

  hipMemsetAsync(flags, 0, 2048, stream);
  xt_k<<<dim3(8192), dim3(256), 0, stream>>>(X, Xt);
  cvt_bf16<<<dim3(64), dim3(256), 0, stream>>>(Wy, Wyb, 16384);

  float* hidout = (float*)d_out + 8388608;

  gru_fused<<<dim3(96), dim3(768), 0, stream>>>(
      Whz, Whr, Whg, bz, br, bg, Wx0z, Wx0r, Wx0g, Wxz, Wxr, Wxg,
      Xt, H0, ring, ubc, flags, Hb, hidout);

  // Y = H2 @ Wy^T + by  -> (B,S,O) fp32
  gemm_bt<<<dim3(512, 1), 256, 0, stream>>>(Hb, Wyb, d_out, by, 65536, 128, 512, 2);
}